// Round 8
// baseline (322.479 us; speedup 1.0000x reference)
//
#include <hip/hip_runtime.h>

#define N_NODES 50000
#define N_EDGES 800000
#define HID 64
#define LAYERS 4
#define MAXDEG 64          // bucket capacity; Poisson(16) max over 50K ~ 40 (12 sigma)
#define NBLK64 782
#define NBLK32 1563

typedef unsigned short u16;
typedef __attribute__((ext_vector_type(8))) __bf16 bf16x8;
typedef __attribute__((ext_vector_type(8))) unsigned short u16x8;
typedef __attribute__((ext_vector_type(4))) float f32x4;
typedef _Float16 f16x2 __attribute__((ext_vector_type(2)));

__device__ __forceinline__ u16 f2bf(float f) {
  unsigned u = __builtin_bit_cast(unsigned, f);
  u += 0x7fffu + ((u >> 16) & 1u);   // RNE
  return (u16)(u >> 16);
}
__device__ __forceinline__ float bf2f(u16 s) {
  return __builtin_bit_cast(float, ((unsigned)s) << 16);
}
__device__ __forceinline__ u16 f2h(float f) {
  return __builtin_bit_cast(u16, (_Float16)f);
}
__device__ __forceinline__ unsigned pkadd(unsigned a, unsigned b) {
  f16x2 r = __builtin_bit_cast(f16x2, a) + __builtin_bit_cast(f16x2, b);
  return __builtin_bit_cast(unsigned, r);
}
__device__ __forceinline__ unsigned pkmax0(unsigned x) {
  unsigned r, z = 0u;
  asm("v_pk_max_f16 %0, %1, %2" : "=v"(r) : "v"(x), "v"(z));
  return r;
}

// ---------------- prep: weights + encoder h ONLY (coalesced, ~7MB writes) ----
// W1abT: [L][128][64] bf16 — cols 0-63 = W1a (src), 64-127 = W1b (dst), [n][k]
// Wvx:   [L][3][64] f32  (We@W1c folded rank-3 edge_vec term)
// b1x:   [L][64] f32     (b1 + be@W1c)
// NB1T:  [L][64][128] bf16 — node GEMM1 B: k<64 = M1a^T, k>=64 = (W2@M1b)^T
// bb2:   [L][64] f32     (b2@M1b — scaled by deg in node epilogue)
// M2T:   [L][64][64] bf16
__global__ __launch_bounds__(256) void prep_kernel(
    const float* __restrict__ nf, const float* __restrict__ enc_w,
    const float* __restrict__ enc_b,
    const float* __restrict__ ew1, const float* __restrict__ eb1,
    const float* __restrict__ ew2, const float* __restrict__ eb2,
    const float* __restrict__ nw1, const float* __restrict__ nw2,
    const float* __restrict__ edge_enc_w, const float* __restrict__ edge_enc_b,
    u16* __restrict__ h, u16* W1abT, float* Wvx, float* b1x,
    u16* NB1T, float* bb2, u16* M2T) {
  const int T = gridDim.x * 256;
  int tid = blockIdx.x * 256 + threadIdx.x;
  // ---- weights ----
  {
    const int szA = LAYERS * 128 * 64, szV = LAYERS * 3 * 64, szB = LAYERS * 64;
    const int szN = LAYERS * 64 * 128, szb2 = LAYERS * 64, szM = LAYERS * 64 * 64;
    const int tot = szA + szV + szB + szN + szb2 + szM;
    for (int i = tid; i < tot; i += T) {
      int idx = i;
      if (idx < szA) {
        int l = idx / (128 * 64); int r = idx % (128 * 64);
        int nfc = r / 64; int k = r % 64;
        int half = nfc >> 6, f = nfc & 63;
        W1abT[idx] = f2bf(ew1[(l * 192 + half * 64 + k) * 64 + f]);
        continue;
      }
      idx -= szA;
      if (idx < szV) {
        int l = idx / 192, r = idx % 192, a = r / 64, f = r % 64;
        float s = 0.f;
        for (int m = 0; m < 64; ++m) s += edge_enc_w[a * 64 + m] * ew1[(l * 192 + 128 + m) * 64 + f];
        Wvx[idx] = s;
        continue;
      }
      idx -= szV;
      if (idx < szB) {
        int l = idx / 64, f = idx % 64;
        float s = eb1[l * 64 + f];
        for (int m = 0; m < 64; ++m) s += edge_enc_b[m] * ew1[(l * 192 + 128 + m) * 64 + f];
        b1x[idx] = s;
        continue;
      }
      idx -= szB;
      if (idx < szN) {
        int l = idx / 8192, r = idx % 8192, f = r / 128, k = r % 128;
        float v;
        if (k < 64) v = nw1[(l * 128 + k) * 64 + f];
        else {
          int j = k - 64; float s = 0.f;
          for (int g = 0; g < 64; ++g)
            s += ew2[(l * 64 + j) * 64 + g] * nw1[(l * 128 + 64 + g) * 64 + f];
          v = s;
        }
        NB1T[idx] = f2bf(v);
        continue;
      }
      idx -= szN;
      if (idx < szb2) {
        int l = idx / 64, f = idx % 64;
        float s = 0.f;
        for (int g = 0; g < 64; ++g) s += eb2[l * 64 + g] * nw1[(l * 128 + 64 + g) * 64 + f];
        bb2[idx] = s;
        continue;
      }
      idx -= szb2;
      int l = idx / 4096, r = idx % 4096, f = r / 64, k = r % 64;
      M2T[idx] = f2bf(nw2[(l * 64 + k) * 64 + f]);
    }
  }
  // ---- encoder h (8 features / thread, 16B stores) ----
  for (int i = tid; i < N_NODES * 8; i += T) {
    int n = i >> 3, j0 = (i & 7) * 8;
    float x0 = nf[n * 3 + 0], x1 = nf[n * 3 + 1], x2 = nf[n * 3 + 2];
    u16x8 v;
#pragma unroll
    for (int j = 0; j < 8; ++j) {
      int jj = j0 + j;
      float s = enc_b[jj] + x0 * enc_w[jj] + x1 * enc_w[64 + jj] + x2 * enc_w[128 + jj];
      v[j] = f2bf(s);
    }
    *(u16x8*)(h + (size_t)n * 64 + j0) = v;
  }
}

// ---------------- susc: su GEMM + bucket scatter (fused; scatter hides) ------
// su: S' = h@W1a − pos·Wv ; U' = h@W1b + pos·Wv + b1  (layer 0, f16 storage)
// scatter: 4 edges/thread preloaded at entry (regs), atomics+stores at end —
// 4-deep atomic ILP + co-residency with MFMA waves hides the latency.
__global__ __launch_bounds__(256) void susc_kernel(
    const u16* __restrict__ h, const u16* __restrict__ W1abT,
    const float* __restrict__ Wvx, const float* __restrict__ b1x,
    const float* __restrict__ pos,
    u16* __restrict__ Sarr, u16* __restrict__ Uarr,
    const int* __restrict__ ei,
    int* __restrict__ cnt, int* __restrict__ srcSlot) {
  __shared__ float sPos[192];
  int t = threadIdx.x;
  int lane = t & 63, wvi = t >> 6;
  int n16 = lane & 15, quad = lane >> 4;
  int n0 = blockIdx.x * 64;

  // ---- scatter edge preload (coalesced; values carried in regs) ----
  const int T = gridDim.x * 256;
  int tid = blockIdx.x * 256 + t;
  int es[4], ed[4]; bool eok[4];
#pragma unroll
  for (int k = 0; k < 4; ++k) {
    int idx = tid + k * T;
    eok[k] = idx < N_EDGES;
    int ii = eok[k] ? idx : 0;
    es[k] = ei[ii];
    ed[k] = ei[N_EDGES + ii];
  }

  if (t < 192) {
    int idx = n0 * 3 + t;
    sPos[t] = (idx < N_NODES * 3) ? pos[idx] : 0.f;
  }
  __syncthreads();

  bf16x8 B[2][2];
  float w0[2], w1[2], w2[2], bb[2]; bool isU[2];
#pragma unroll
  for (int nt = 0; nt < 2; ++nt) {
    int col = wvi * 32 + nt * 16 + n16;
    const u16* p = W1abT + (size_t)col * 64 + quad * 8;   // layer 0
    B[nt][0] = __builtin_bit_cast(bf16x8, *(const u16x8*)(p));
    B[nt][1] = __builtin_bit_cast(bf16x8, *(const u16x8*)(p + 32));
    int f = col & 63; isU[nt] = col >= 64;
    w0[nt] = Wvx[f];
    w1[nt] = Wvx[64 + f];
    w2[nt] = Wvx[128 + f];
    bb[nt] = b1x[f];
  }
  f32x4 acc[4][2];
#pragma unroll
  for (int m = 0; m < 4; ++m)
#pragma unroll
    for (int nt = 0; nt < 2; ++nt) acc[m][nt] = (f32x4){0.f, 0.f, 0.f, 0.f};
#pragma unroll
  for (int m = 0; m < 4; ++m) {
    int row = n0 + m * 16 + n16;
    if (row >= N_NODES) row = N_NODES - 1;
    const u16* hp = h + (size_t)row * 64 + quad * 8;
    bf16x8 a0 = __builtin_bit_cast(bf16x8, *(const u16x8*)(hp));
    bf16x8 a1 = __builtin_bit_cast(bf16x8, *(const u16x8*)(hp + 32));
#pragma unroll
    for (int nt = 0; nt < 2; ++nt) {
      acc[m][nt] = __builtin_amdgcn_mfma_f32_16x16x32_bf16(a0, B[nt][0], acc[m][nt], 0, 0, 0);
      acc[m][nt] = __builtin_amdgcn_mfma_f32_16x16x32_bf16(a1, B[nt][1], acc[m][nt], 0, 0, 0);
    }
  }
#pragma unroll
  for (int m = 0; m < 4; ++m)
#pragma unroll
    for (int nt = 0; nt < 2; ++nt) {
      int col = wvi * 32 + nt * 16 + n16;
      int f = col & 63;
#pragma unroll
      for (int r = 0; r < 4; ++r) {
        int e = m * 16 + quad * 4 + r;
        int grow = n0 + e;
        if (grow < N_NODES) {
          float P = sPos[e * 3] * w0[nt] + sPos[e * 3 + 1] * w1[nt] + sPos[e * 3 + 2] * w2[nt];
          if (!isU[nt]) Sarr[(size_t)grow * 64 + f] = f2h(acc[m][nt][r] - P);
          else          Uarr[(size_t)grow * 64 + f] = f2h(acc[m][nt][r] + P + bb[nt]);
        }
      }
    }

  // ---- bucket scatter: 4 independent atomics in flight, then 4 stores ----
  int er[4];
#pragma unroll
  for (int k = 0; k < 4; ++k)
    er[k] = eok[k] ? atomicAdd(&cnt[ed[k]], 1) : MAXDEG;
#pragma unroll
  for (int k = 0; k < 4; ++k)
    if (er[k] < MAXDEG) srcSlot[(ed[k] << 6) + er[k]] = es[k] << 7;
}

// ---------------- fused layer: ep (LDS agg) + node MLP, 32-node tiles -------
// Bucket staging is static-address: block b stages srcSlot[b*2048 .. b*2048+2048)
// immediately (no offs dependency). Garbage slots (j >= deg) are masked by a
// select AFTER the LDS read (safe row-0 address), never dereferenced raw.
__global__ __launch_bounds__(256) void layer_kernel(
    const u16* __restrict__ h, const int* __restrict__ srcSlot,
    const int* __restrict__ cnt,
    const u16* __restrict__ Sr, const u16* __restrict__ Ur,
    const u16* __restrict__ NB1T, const float* __restrict__ nb1,
    const float* __restrict__ bb2,
    const u16* __restrict__ M2T, const float* __restrict__ nb2,
    u16* __restrict__ hnext, int layer,
    const u16* __restrict__ W1abT, const float* __restrict__ Wvx,
    const float* __restrict__ b1x, const float* __restrict__ pos,
    u16* __restrict__ Sw, u16* __restrict__ Uw,
    const float* __restrict__ dec_w, const float* __restrict__ dec_b,
    float* __restrict__ out) {
  __shared__ int sIdx[32 * MAXDEG];
  __shared__ int sDeg[32];
  __shared__ u16 aggT[32 * 72];
  __shared__ u16 Hs[32 * 72];
  __shared__ float sPos[96];
  __shared__ float sRed[32][8];
  int t = threadIdx.x;
  int lane = t & 63, wvi = t >> 6;
  int n16 = lane & 15, quad = lane >> 4;
  int F = wvi * 16;
  int n0 = blockIdx.x * 32;

  if (t < 32) {
    int gn = n0 + t;
    int dg = (gn < N_NODES) ? cnt[gn] : 0;
    sDeg[t] = dg > MAXDEG ? MAXDEG : dg;
  }
  if (t >= 64 && t < 160) {
    int i = t - 64;
    int idx = n0 * 3 + i;
    sPos[i] = (idx < N_NODES * 3) ? pos[idx] : 0.f;
  }
  {
    int sbase = n0 << 6;   // = blockIdx.x * 2048
    for (int i = t; i < 32 * MAXDEG; i += 256) sIdx[i] = srcSlot[sbase + i];
  }
  __syncthreads();

  // ==== ep phase: aggT[d] = sum_e relu(S'[src] + U'[d]), packed f16 ====
  {
    int c = lane & 31, half = lane >> 5;
    unsigned cbu = (unsigned)(c << 2);
    const char* __restrict__ Sb = (const char*)Sr;
    const char* __restrict__ Ub = (const char*)Ur;
    for (int i = 0; i < 8; i += 2) {
      int lnA = wvi * 8 + i;
      int dA = n0 + lnA;
      int degA = sDeg[lnA], degB = sDeg[lnA + 1];
      int relA = lnA << 6, relB = relA + 64;
      int dAc = dA < N_NODES ? dA : N_NODES - 1;
      int dBc = (dA + 1) < N_NODES ? (dA + 1) : N_NODES - 1;
      unsigned upA = *(const unsigned*)(Ub + (size_t)dAc * 128 + cbu);
      unsigned upB = *(const unsigned*)(Ub + (size_t)dBc * 128 + cbu);
      float saA = 0.f, sbA = 0.f, saB = 0.f, sbB = 0.f;
      int degMin = degA < degB ? degA : degB;
      int degMax = degA > degB ? degA : degB;
      int fullr = degMin >> 4;
      int rmax = (degMax + 15) >> 4;
      int r = 0;
      for (; r < fullr; ++r) {               // mask-free (both nodes full)
        int base = r * 16 + half;
        unsigned wA[8], wB[8];
#pragma unroll
        for (int kk = 0; kk < 8; ++kk) {
          int j = base + 2 * kk;
          wA[kk] = *(const unsigned*)(Sb + (unsigned)sIdx[relA + j] + cbu);
          wB[kk] = *(const unsigned*)(Sb + (unsigned)sIdx[relB + j] + cbu);
        }
        unsigned pA = 0u, pB = 0u;
#pragma unroll
        for (int kk = 0; kk < 8; ++kk) {
          pA = pkadd(pA, pkmax0(pkadd(wA[kk], upA)));
          pB = pkadd(pB, pkmax0(pkadd(wB[kk], upB)));
        }
        f16x2 hA2 = __builtin_bit_cast(f16x2, pA);
        f16x2 hB2 = __builtin_bit_cast(f16x2, pB);
        saA += (float)hA2[0]; sbA += (float)hA2[1];
        saB += (float)hB2[0]; sbB += (float)hB2[1];
      }
      for (; r < rmax; ++r) {                // masked remainder
        int base = r * 16 + half;
        unsigned wA[8], wB[8]; bool okA[8], okB[8];
#pragma unroll
        for (int kk = 0; kk < 8; ++kk) {
          int j = base + 2 * kk;
          okA[kk] = j < degA;
          int vA = sIdx[relA + j];           // in-bounds LDS (j < 64)
          vA = okA[kk] ? vA : 0;             // safe row-0 address when masked
          wA[kk] = *(const unsigned*)(Sb + (unsigned)vA + cbu);
          okB[kk] = j < degB;
          int vB = sIdx[relB + j];
          vB = okB[kk] ? vB : 0;
          wB[kk] = *(const unsigned*)(Sb + (unsigned)vB + cbu);
        }
        unsigned pA = 0u, pB = 0u;
#pragma unroll
        for (int kk = 0; kk < 8; ++kk) {
          unsigned zA = pkmax0(pkadd(wA[kk], upA));
          pA = pkadd(pA, okA[kk] ? zA : 0u);
          unsigned zB = pkmax0(pkadd(wB[kk], upB));
          pB = pkadd(pB, okB[kk] ? zB : 0u);
        }
        f16x2 hA2 = __builtin_bit_cast(f16x2, pA);
        f16x2 hB2 = __builtin_bit_cast(f16x2, pB);
        saA += (float)hA2[0]; sbA += (float)hA2[1];
        saB += (float)hB2[0]; sbB += (float)hB2[1];
      }
      saA += __shfl_xor(saA, 32);  sbA += __shfl_xor(sbA, 32);
      saB += __shfl_xor(saB, 32);  sbB += __shfl_xor(sbB, 32);
      if (half == 0) {
        unsigned pk = (unsigned)f2bf(saA) | ((unsigned)f2bf(sbA) << 16);
        *(unsigned*)((char*)aggT + (size_t)lnA * 144 + cbu) = pk;
        unsigned pk2 = (unsigned)f2bf(saB) | ((unsigned)f2bf(sbB) << 16);
        *(unsigned*)((char*)aggT + (size_t)(lnA + 1) * 144 + cbu) = pk2;
      }
    }
  }
  __syncthreads();

  // ==== node MLP ====
  bf16x8 B1[4], B2[2];
  {
    const u16* p = NB1T + (size_t)(layer * 64 + F + n16) * 128 + quad * 8;
#pragma unroll
    for (int ks = 0; ks < 4; ++ks) B1[ks] = __builtin_bit_cast(bf16x8, *(const u16x8*)(p + ks * 32));
    const u16* q = M2T + (size_t)(layer * 64 + F + n16) * 64 + quad * 8;
#pragma unroll
    for (int ks = 0; ks < 2; ++ks) B2[ks] = __builtin_bit_cast(bf16x8, *(const u16x8*)(q + ks * 32));
  }
  float bias1 = nb1[layer * 64 + F + n16];
  float bb2f = bb2[layer * 64 + F + n16];
  float bias2 = nb2[layer * 64 + F + n16];

  // GEMM1: [h | aggT] @ NB1T (32 rows)
  f32x4 acc[2];
#pragma unroll
  for (int m = 0; m < 2; ++m) acc[m] = (f32x4){0.f, 0.f, 0.f, 0.f};
#pragma unroll
  for (int m = 0; m < 2; ++m) {
    int row = n0 + m * 16 + n16;
    if (row >= N_NODES) row = N_NODES - 1;
    const u16* hp = h + (size_t)row * 64 + quad * 8;
    const u16* ap = aggT + (m * 16 + n16) * 72 + quad * 8;
    bf16x8 a0 = __builtin_bit_cast(bf16x8, *(const u16x8*)(hp));
    bf16x8 a1 = __builtin_bit_cast(bf16x8, *(const u16x8*)(hp + 32));
    bf16x8 a2 = __builtin_bit_cast(bf16x8, *(const u16x8*)(ap));
    bf16x8 a3 = __builtin_bit_cast(bf16x8, *(const u16x8*)(ap + 32));
    acc[m] = __builtin_amdgcn_mfma_f32_16x16x32_bf16(a0, B1[0], acc[m], 0, 0, 0);
    acc[m] = __builtin_amdgcn_mfma_f32_16x16x32_bf16(a1, B1[1], acc[m], 0, 0, 0);
    acc[m] = __builtin_amdgcn_mfma_f32_16x16x32_bf16(a2, B1[2], acc[m], 0, 0, 0);
    acc[m] = __builtin_amdgcn_mfma_f32_16x16x32_bf16(a3, B1[3], acc[m], 0, 0, 0);
  }
#pragma unroll
  for (int m = 0; m < 2; ++m)
#pragma unroll
    for (int r = 0; r < 4; ++r) {
      int e = m * 16 + quad * 4 + r;
      float v = acc[m][r] + bias1 + (float)sDeg[e] * bb2f;
      v = v > 0.f ? v : 0.f;
      Hs[e * 72 + F + n16] = f2bf(v);
    }
  __syncthreads();

  // GEMM2: hidden @ M2T -> h2 (registers)
  float c2[2][4];
#pragma unroll
  for (int m = 0; m < 2; ++m) {
    const u16* hp = Hs + (m * 16 + n16) * 72 + quad * 8;
    f32x4 cc = (f32x4){0.f, 0.f, 0.f, 0.f};
#pragma unroll
    for (int ks = 0; ks < 2; ++ks) {
      bf16x8 a = __builtin_bit_cast(bf16x8, *(const u16x8*)(hp + ks * 32));
      cc = __builtin_amdgcn_mfma_f32_16x16x32_bf16(a, B2[ks], cc, 0, 0, 0);
    }
#pragma unroll
    for (int r = 0; r < 4; ++r) c2[m][r] = cc[r] + bias2;
  }
  __syncthreads();   // all Hs reads done

  // h2 -> LDS (+ global if another layer follows)
#pragma unroll
  for (int m = 0; m < 2; ++m)
#pragma unroll
    for (int r = 0; r < 4; ++r) {
      int e = m * 16 + quad * 4 + r;
      u16 hv = f2bf(c2[m][r]);
      Hs[e * 72 + F + n16] = hv;
      int gn = n0 + e;
      if (layer < LAYERS - 1 && gn < N_NODES)
        hnext[(size_t)gn * 64 + F + n16] = hv;
    }
  __syncthreads();

  if (layer < LAYERS - 1) {
    int lp = layer + 1;
    bf16x8 B3[2][2];
    float w0[2], w1[2], w2[2], bb[2]; bool isU[2];
#pragma unroll
    for (int nt = 0; nt < 2; ++nt) {
      int col = wvi * 32 + nt * 16 + n16;
      const u16* p = W1abT + (size_t)(lp * 128 + col) * 64 + quad * 8;
      B3[nt][0] = __builtin_bit_cast(bf16x8, *(const u16x8*)(p));
      B3[nt][1] = __builtin_bit_cast(bf16x8, *(const u16x8*)(p + 32));
      int f = col & 63; isU[nt] = col >= 64;
      w0[nt] = Wvx[(lp * 3 + 0) * 64 + f];
      w1[nt] = Wvx[(lp * 3 + 1) * 64 + f];
      w2[nt] = Wvx[(lp * 3 + 2) * 64 + f];
      bb[nt] = b1x[lp * 64 + f];
    }
    f32x4 a3[2][2];
#pragma unroll
    for (int m = 0; m < 2; ++m)
#pragma unroll
      for (int nt = 0; nt < 2; ++nt) a3[m][nt] = (f32x4){0.f, 0.f, 0.f, 0.f};
#pragma unroll
    for (int m = 0; m < 2; ++m) {
      const u16* hp = Hs + (m * 16 + n16) * 72 + quad * 8;
      bf16x8 a0 = __builtin_bit_cast(bf16x8, *(const u16x8*)(hp));
      bf16x8 a1 = __builtin_bit_cast(bf16x8, *(const u16x8*)(hp + 32));
#pragma unroll
      for (int nt = 0; nt < 2; ++nt) {
        a3[m][nt] = __builtin_amdgcn_mfma_f32_16x16x32_bf16(a0, B3[nt][0], a3[m][nt], 0, 0, 0);
        a3[m][nt] = __builtin_amdgcn_mfma_f32_16x16x32_bf16(a1, B3[nt][1], a3[m][nt], 0, 0, 0);
      }
    }
#pragma unroll
    for (int m = 0; m < 2; ++m)
#pragma unroll
      for (int nt = 0; nt < 2; ++nt) {
        int col = wvi * 32 + nt * 16 + n16;
        int f = col & 63;
#pragma unroll
        for (int r = 0; r < 4; ++r) {
          int e = m * 16 + quad * 4 + r;
          int grow = n0 + e;
          if (grow < N_NODES) {
            float P = sPos[e * 3] * w0[nt] + sPos[e * 3 + 1] * w1[nt] + sPos[e * 3 + 2] * w2[nt];
            if (!isU[nt]) Sw[(size_t)grow * 64 + f] = f2h(a3[m][nt][r] - P);
            else          Uw[(size_t)grow * 64 + f] = f2h(a3[m][nt][r] + P + bb[nt]);
          }
        }
      }
  } else {
    // fused decoder: out = h2 @ dec_w + dec_b
    int e = t >> 3, part = t & 7;
    float s = 0.f;
#pragma unroll
    for (int j = 0; j < 8; ++j)
      s += bf2f(Hs[e * 72 + part * 8 + j]) * dec_w[part * 8 + j];
    sRed[e][part] = s;
    __syncthreads();
    if (part == 0) {
      int gn = n0 + e;
      if (gn < N_NODES) {
        float acc8 = dec_b[0];
#pragma unroll
        for (int p2 = 0; p2 < 8; ++p2) acc8 += sRed[e][p2];
        out[gn] = acc8;
      }
    }
  }
}

extern "C" void kernel_launch(void* const* d_in, const int* in_sizes, int n_in,
                              void* d_out, int out_size, void* d_ws, size_t ws_size,
                              hipStream_t stream) {
  const float* node_pos   = (const float*)d_in[0];
  const float* node_feat  = (const float*)d_in[1];
  const int*   edge_index = (const int*)d_in[2];
  const float* enc_w      = (const float*)d_in[3];
  const float* enc_b      = (const float*)d_in[4];
  const float* edge_enc_w = (const float*)d_in[5];
  const float* edge_enc_b = (const float*)d_in[6];
  const float* ew1        = (const float*)d_in[7];
  const float* eb1        = (const float*)d_in[8];
  const float* ew2        = (const float*)d_in[9];
  const float* eb2        = (const float*)d_in[10];
  const float* nw1        = (const float*)d_in[11];
  const float* nb1        = (const float*)d_in[12];
  const float* nw2        = (const float*)d_in[13];
  const float* nb2        = (const float*)d_in[14];
  const float* dec_w      = (const float*)d_in[15];
  const float* dec_b      = (const float*)d_in[16];
  float* out = (float*)d_out;

  char* ws = (char*)d_ws;
  size_t off = 0;
  u16*    hA    = (u16*)(ws + off);    off += (size_t)N_NODES * 64 * 2;
  u16*    hB    = (u16*)(ws + off);    off += (size_t)N_NODES * 64 * 2;
  u16*    S0    = (u16*)(ws + off);    off += (size_t)N_NODES * 64 * 2;
  u16*    U0    = (u16*)(ws + off);    off += (size_t)N_NODES * 64 * 2;
  u16*    S1    = (u16*)(ws + off);    off += (size_t)N_NODES * 64 * 2;
  u16*    U1    = (u16*)(ws + off);    off += (size_t)N_NODES * 64 * 2;
  u16*    W1abT = (u16*)(ws + off);    off += (size_t)LAYERS * 128 * 64 * 2;
  float*  Wvx   = (float*)(ws + off);  off += (size_t)LAYERS * 3 * 64 * 4;
  float*  b1x   = (float*)(ws + off);  off += (size_t)LAYERS * 64 * 4;
  u16*    NB1T  = (u16*)(ws + off);    off += (size_t)LAYERS * 64 * 128 * 2;
  float*  bb2   = (float*)(ws + off);  off += (size_t)LAYERS * 64 * 4;
  u16*    M2T   = (u16*)(ws + off);    off += (size_t)LAYERS * 64 * 64 * 2;
  int*    cnt      = (int*)(ws + off); off += (size_t)N_NODES * 4;
  // srcSlot padded to 50048 nodes so the tail block's static 2048-slot stage
  // stays inside the allocation
  int*    srcSlot  = (int*)(ws + off); off += (size_t)50048 * MAXDEG * 4;

  hipMemsetAsync(cnt, 0, (size_t)N_NODES * 4, stream);

  prep_kernel<<<1024, 256, 0, stream>>>(
      node_feat, enc_w, enc_b, ew1, eb1, ew2, eb2, nw1, nw2,
      edge_enc_w, edge_enc_b,
      hA, W1abT, Wvx, b1x, NB1T, bb2, M2T);

  susc_kernel<<<NBLK64, 256, 0, stream>>>(hA, W1abT, Wvx, b1x, node_pos,
                                          S0, U0, edge_index, cnt, srcSlot);

  u16 *hc = hA, *hn = hB, *Sr = S0, *Ur = U0, *Sw = S1, *Uw = U1;
  for (int l = 0; l < LAYERS; ++l) {
    layer_kernel<<<NBLK32, 256, 0, stream>>>(hc, srcSlot, cnt, Sr, Ur,
                                             NB1T, nb1, bb2, M2T, nb2,
                                             hn, l, W1abT, Wvx, b1x, node_pos,
                                             Sw, Uw, dec_w, dec_b, out);
    u16* tmp;
    tmp = hc; hc = hn; hn = tmp;
    tmp = Sr; Sr = Sw; Sw = tmp;
    tmp = Ur; Ur = Uw; Uw = tmp;
  }
}

// Round 9
// 293.942 us; speedup vs baseline: 1.0971x; 1.0971x over previous
//
#include <hip/hip_runtime.h>

#define N_NODES 50000
#define N_EDGES 800000
#define HID 64
#define LAYERS 4
#define EP_CAP 2048        // staged srcS capacity per 32-node tile (avg ~512)
#define SCAN_NBLK 25
#define NBLK64 782
#define NBLK32 1563

typedef unsigned short u16;
typedef __attribute__((ext_vector_type(8))) __bf16 bf16x8;
typedef __attribute__((ext_vector_type(8))) unsigned short u16x8;
typedef __attribute__((ext_vector_type(4))) float f32x4;
typedef _Float16 f16x2 __attribute__((ext_vector_type(2)));
typedef __attribute__((ext_vector_type(2))) unsigned uint2v;

__device__ __forceinline__ u16 f2bf(float f) {
  unsigned u = __builtin_bit_cast(unsigned, f);
  u += 0x7fffu + ((u >> 16) & 1u);   // RNE
  return (u16)(u >> 16);
}
__device__ __forceinline__ float bf2f(u16 s) {
  return __builtin_bit_cast(float, ((unsigned)s) << 16);
}
__device__ __forceinline__ u16 f2h(float f) {
  return __builtin_bit_cast(u16, (_Float16)f);
}
__device__ __forceinline__ unsigned pkadd(unsigned a, unsigned b) {
  f16x2 r = __builtin_bit_cast(f16x2, a) + __builtin_bit_cast(f16x2, b);
  return __builtin_bit_cast(unsigned, r);
}
__device__ __forceinline__ unsigned pkmax0(unsigned x) {
  unsigned r, z = 0u;
  asm("v_pk_max_f16 %0, %1, %2" : "=v"(r) : "v"(x), "v"(z));
  return r;
}

// ---------------- prep: weight prep + encoder h + hist/rank (one launch) -----
// (cnt zeroed by preceding memset)
// W1abT: [L][128][64] bf16 — cols 0-63 = W1a (src), 64-127 = W1b (dst), [n][k]
// Wvx:   [L][3][64] f32  (We@W1c folded rank-3 edge_vec term)
// b1x:   [L][64] f32     (b1 + be@W1c)
// NB1T:  [L][64][128] bf16 — node GEMM1 B: k<64 = M1a^T, k>=64 = (W2@M1b)^T
// bb2:   [L][64] f32     (b2@M1b — scaled by deg in node epilogue)
// M2T:   [L][64][64] bf16
__global__ __launch_bounds__(256) void prep_kernel(
    const float* __restrict__ nf, const float* __restrict__ enc_w,
    const float* __restrict__ enc_b,
    const float* __restrict__ ew1, const float* __restrict__ eb1,
    const float* __restrict__ ew2, const float* __restrict__ eb2,
    const float* __restrict__ nw1, const float* __restrict__ nw2,
    const float* __restrict__ edge_enc_w, const float* __restrict__ edge_enc_b,
    const int* __restrict__ dstA,
    u16* __restrict__ h, u16* W1abT, float* Wvx, float* b1x,
    u16* NB1T, float* bb2, u16* M2T,
    int* __restrict__ cnt, int* __restrict__ rank) {
  const int T = gridDim.x * 256;
  int tid = blockIdx.x * 256 + threadIdx.x;
  // ---- weights ----
  {
    const int szA = LAYERS * 128 * 64, szV = LAYERS * 3 * 64, szB = LAYERS * 64;
    const int szN = LAYERS * 64 * 128, szb2 = LAYERS * 64, szM = LAYERS * 64 * 64;
    const int tot = szA + szV + szB + szN + szb2 + szM;
    for (int i = tid; i < tot; i += T) {
      int idx = i;
      if (idx < szA) {
        int l = idx / (128 * 64); int r = idx % (128 * 64);
        int nfc = r / 64; int k = r % 64;
        int half = nfc >> 6, f = nfc & 63;
        W1abT[idx] = f2bf(ew1[(l * 192 + half * 64 + k) * 64 + f]);
        continue;
      }
      idx -= szA;
      if (idx < szV) {
        int l = idx / 192, r = idx % 192, a = r / 64, f = r % 64;
        float s = 0.f;
        for (int m = 0; m < 64; ++m) s += edge_enc_w[a * 64 + m] * ew1[(l * 192 + 128 + m) * 64 + f];
        Wvx[idx] = s;
        continue;
      }
      idx -= szV;
      if (idx < szB) {
        int l = idx / 64, f = idx % 64;
        float s = eb1[l * 64 + f];
        for (int m = 0; m < 64; ++m) s += edge_enc_b[m] * ew1[(l * 192 + 128 + m) * 64 + f];
        b1x[idx] = s;
        continue;
      }
      idx -= szB;
      if (idx < szN) {
        int l = idx / 8192, r = idx % 8192, f = r / 128, k = r % 128;
        float v;
        if (k < 64) v = nw1[(l * 128 + k) * 64 + f];
        else {
          int j = k - 64; float s = 0.f;
          for (int g = 0; g < 64; ++g)
            s += ew2[(l * 64 + j) * 64 + g] * nw1[(l * 128 + 64 + g) * 64 + f];
          v = s;
        }
        NB1T[idx] = f2bf(v);
        continue;
      }
      idx -= szN;
      if (idx < szb2) {
        int l = idx / 64, f = idx % 64;
        float s = 0.f;
        for (int g = 0; g < 64; ++g) s += eb2[l * 64 + g] * nw1[(l * 128 + 64 + g) * 64 + f];
        bb2[idx] = s;
        continue;
      }
      idx -= szb2;
      int l = idx / 4096, r = idx % 4096, f = r / 64, k = r % 64;
      M2T[idx] = f2bf(nw2[(l * 64 + k) * 64 + f]);
    }
  }
  // ---- encoder h (8 features / thread, 16B stores) ----
  for (int i = tid; i < N_NODES * 8; i += T) {
    int n = i >> 3, j0 = (i & 7) * 8;
    float x0 = nf[n * 3 + 0], x1 = nf[n * 3 + 1], x2 = nf[n * 3 + 2];
    u16x8 v;
#pragma unroll
    for (int j = 0; j < 8; ++j) {
      int jj = j0 + j;
      float s = enc_b[jj] + x0 * enc_w[jj] + x1 * enc_w[64 + jj] + x2 * enc_w[128 + jj];
      v[j] = f2bf(s);
    }
    *(u16x8*)(h + (size_t)n * 64 + j0) = v;
  }
  // ---- hist + rank ----
  for (int idx = tid; idx < N_EDGES; idx += T)
    rank[idx] = atomicAdd(&cnt[dstA[idx]], 1);
}

// ---------------- scan1: per-2048-block local scan + raw partials ------------
__global__ __launch_bounds__(256) void scan1_kernel(const int* __restrict__ cnt,
                                                    int* __restrict__ offs,
                                                    int* __restrict__ partials) {
  __shared__ int sm[2048];
  __shared__ int ws2[256];
  int t = threadIdx.x, b = blockIdx.x;
  int base = b * 2048;
#pragma unroll
  for (int i = 0; i < 8; ++i) {
    int idx = base + i * 256 + t;
    sm[i * 256 + t] = (idx < N_NODES) ? cnt[idx] : 0;
  }
  __syncthreads();
  int loc[8]; int s = 0;
#pragma unroll
  for (int i = 0; i < 8; ++i) { loc[i] = s; s += sm[t * 8 + i]; }
  ws2[t] = s;
  __syncthreads();
  for (int off = 1; off < 256; off <<= 1) {
    int u = (t >= off) ? ws2[t - off] : 0;
    __syncthreads();
    ws2[t] += u;
    __syncthreads();
  }
  int tbase = (t > 0) ? ws2[t - 1] : 0;
  if (t == 255) partials[b] = ws2[255];
#pragma unroll
  for (int i = 0; i < 8; ++i) {
    int idx = base + t * 8 + i;
    if (idx < N_NODES) offs[idx] = tbase + loc[i];
  }
}

// ---------------- fss: su (b<782) + offs finalize + scatter (one launch) -----
// su: S' = h@W1a − pos·Wv ; U' = h@W1b + pos·Wv + b1 (layer 0, f16 storage)
// offs2[idx] = offs[idx] + psum[idx>>11]  (scan3 folded in)
// scatter: srcB[offs[d]+psum[d>>11]+rank[e]] = src<<7  (atomic-free)
__global__ __launch_bounds__(256) void fss_kernel(
    const u16* __restrict__ h, const u16* __restrict__ W1abT,
    const float* __restrict__ Wvx, const float* __restrict__ b1x,
    const float* __restrict__ pos,
    u16* __restrict__ Sarr, u16* __restrict__ Uarr,
    const int* __restrict__ offs, const int* __restrict__ partials,
    const int* __restrict__ ei, const int* __restrict__ rank,
    int* __restrict__ srcB, int* __restrict__ offs2) {
  __shared__ float sPos[192];
  __shared__ int psum[32];
  int t = threadIdx.x, b = blockIdx.x;

  if (b < NBLK64) {
    // ---- su tile (64 nodes) ----
    int lane = t & 63, wvi = t >> 6;
    int n16 = lane & 15, quad = lane >> 4;
    int n0 = b * 64;
    if (t < 192) {
      int idx = n0 * 3 + t;
      sPos[t] = (idx < N_NODES * 3) ? pos[idx] : 0.f;
    }
    __syncthreads();

    bf16x8 B[2][2];
    float w0[2], w1[2], w2[2], bb[2]; bool isU[2];
#pragma unroll
    for (int nt = 0; nt < 2; ++nt) {
      int col = wvi * 32 + nt * 16 + n16;
      const u16* p = W1abT + (size_t)col * 64 + quad * 8;   // layer 0
      B[nt][0] = __builtin_bit_cast(bf16x8, *(const u16x8*)(p));
      B[nt][1] = __builtin_bit_cast(bf16x8, *(const u16x8*)(p + 32));
      int f = col & 63; isU[nt] = col >= 64;
      w0[nt] = Wvx[f];
      w1[nt] = Wvx[64 + f];
      w2[nt] = Wvx[128 + f];
      bb[nt] = b1x[f];
    }
    f32x4 acc[4][2];
#pragma unroll
    for (int m = 0; m < 4; ++m)
#pragma unroll
      for (int nt = 0; nt < 2; ++nt) acc[m][nt] = (f32x4){0.f, 0.f, 0.f, 0.f};
#pragma unroll
    for (int m = 0; m < 4; ++m) {
      int row = n0 + m * 16 + n16;
      if (row >= N_NODES) row = N_NODES - 1;
      const u16* hp = h + (size_t)row * 64 + quad * 8;
      bf16x8 a0 = __builtin_bit_cast(bf16x8, *(const u16x8*)(hp));
      bf16x8 a1 = __builtin_bit_cast(bf16x8, *(const u16x8*)(hp + 32));
#pragma unroll
      for (int nt = 0; nt < 2; ++nt) {
        acc[m][nt] = __builtin_amdgcn_mfma_f32_16x16x32_bf16(a0, B[nt][0], acc[m][nt], 0, 0, 0);
        acc[m][nt] = __builtin_amdgcn_mfma_f32_16x16x32_bf16(a1, B[nt][1], acc[m][nt], 0, 0, 0);
      }
    }
#pragma unroll
    for (int m = 0; m < 4; ++m)
#pragma unroll
      for (int nt = 0; nt < 2; ++nt) {
        int col = wvi * 32 + nt * 16 + n16;
        int f = col & 63;
#pragma unroll
        for (int r = 0; r < 4; ++r) {
          int e = m * 16 + quad * 4 + r;
          int grow = n0 + e;
          if (grow < N_NODES) {
            float P = sPos[e * 3] * w0[nt] + sPos[e * 3 + 1] * w1[nt] + sPos[e * 3 + 2] * w2[nt];
            if (!isU[nt]) Sarr[(size_t)grow * 64 + f] = f2h(acc[m][nt][r] - P);
            else          Uarr[(size_t)grow * 64 + f] = f2h(acc[m][nt][r] + P + bb[nt]);
          }
        }
      }
  }

  // ---- 25-partial prefix ----
  if (t == 0) {
    int s = 0;
#pragma unroll
    for (int i = 0; i < SCAN_NBLK; ++i) { psum[i] = s; s += partials[i]; }
  }
  __syncthreads();

  int tid = b * 256 + t;
  const int T = gridDim.x * 256;
  // ---- offs finalize ----
  for (int idx = tid; idx < N_NODES; idx += T)
    offs2[idx] = offs[idx] + psum[idx >> 11];
  // ---- scatter (atomic-free; inline-finalized offsets) ----
  for (int idx = tid; idx < N_EDGES; idx += T) {
    int s = ei[idx], d = ei[N_EDGES + idx];
    srcB[offs[d] + psum[d >> 11] + rank[idx]] = s << 7;
  }
}

// ---------------- fused layer: ep (LDS agg) + node MLP, 32-node tiles -------
// ep gather widened to dwordx2: lane = (feature-quad c4, edge-quarter q);
// one 8B load = 4 features x 1 edge; one wave-load covers 4 edge-rows.
// Per 32 edges: 8 load-inst + 8 LDS idx reads (was 16+16). Node-pair
// interleave keeps 16 loads in flight. 2-stage shfl_xor(16/32) reduce.
__global__ __launch_bounds__(256) void layer_kernel(
    const u16* __restrict__ h, const int* __restrict__ srcB,
    const int* __restrict__ offs,
    const u16* __restrict__ Sr, const u16* __restrict__ Ur,
    const u16* __restrict__ NB1T, const float* __restrict__ nb1,
    const float* __restrict__ bb2,
    const u16* __restrict__ M2T, const float* __restrict__ nb2,
    u16* __restrict__ hnext, int layer,
    const u16* __restrict__ W1abT, const float* __restrict__ Wvx,
    const float* __restrict__ b1x, const float* __restrict__ pos,
    u16* __restrict__ Sw, u16* __restrict__ Uw,
    const float* __restrict__ dec_w, const float* __restrict__ dec_b,
    float* __restrict__ out) {
  __shared__ int sIdx[EP_CAP];
  __shared__ int sOff[33];
  __shared__ u16 aggT[32 * 72];
  __shared__ u16 Hs[32 * 72];
  __shared__ float sPos[96];
  __shared__ float sRed[32][8];
  int t = threadIdx.x;
  int lane = t & 63, wvi = t >> 6;
  int n16 = lane & 15, quad = lane >> 4;
  int F = wvi * 16;
  int n0 = blockIdx.x * 32;

  if (t <= 32) {
    int d = n0 + t;
    sOff[t] = (d < N_NODES) ? offs[d] : N_EDGES;
  }
  if (t >= 64 && t < 160) {
    int i = t - 64;
    int idx = n0 * 3 + i;
    sPos[i] = (idx < N_NODES * 3) ? pos[idx] : 0.f;
  }
  __syncthreads();
  int eS = sOff[0];
  int nE = sOff[32] - eS;
  bool fit = (nE <= EP_CAP);
  if (fit) {
    for (int i = t; i < nE; i += 256) sIdx[i] = srcB[eS + i];
    if (t == 0 && nE < EP_CAP) sIdx[nE] = 0;   // safe pad for deg-0 nodes
  }
  __syncthreads();

  // ==== ep phase: aggT[d] = sum_e relu(S'[src] + U'[d]), packed f16 ====
  {
    int c4 = lane & 15, q = lane >> 4;            // feature-quad, edge-quarter
    unsigned cbu = (unsigned)(c4 << 3);           // byte offset of 4 features
    const char* __restrict__ Sb = (const char*)Sr;
    const char* __restrict__ Ub = (const char*)Ur;
    for (int i = 0; i < 8; i += 2) {
      int lnA = wvi * 8 + i;
      int dA = n0 + lnA;
      int e0A = sOff[lnA], degA = sOff[lnA + 1] - e0A;
      int e0B = sOff[lnA + 1], degB = sOff[lnA + 2] - e0B;
      int dAc = dA < N_NODES ? dA : N_NODES - 1;
      int dBc = (dA + 1) < N_NODES ? (dA + 1) : N_NODES - 1;
      uint2v upA = *(const uint2v*)(Ub + (size_t)dAc * 128 + cbu);
      uint2v upB = *(const uint2v*)(Ub + (size_t)dBc * 128 + cbu);
      float fA0 = 0.f, fA1 = 0.f, fA2 = 0.f, fA3 = 0.f;
      float fB0 = 0.f, fB1 = 0.f, fB2 = 0.f, fB3 = 0.f;
      int relA = (degA > 0) ? (e0A - eS) : 0;
      int relB = (degB > 0) ? (e0B - eS) : 0;
      int g0A = (degA > 0) ? e0A : 0;
      int g0B = (degB > 0) ? e0B : 0;
      int degMin = degA < degB ? degA : degB;
      int degMax = degA > degB ? degA : degB;
      int fullr = degMin >> 5;                     // 32-slot rounds
      int rmax = (degMax + 31) >> 5;
      int r = 0;
      if (fit) {
        for (; r < fullr; ++r) {                   // mask-free (both full)
          int base = r * 32 + q;
          uint2v wA[8], wB[8];
#pragma unroll
          for (int kk = 0; kk < 8; ++kk) {
            int j = base + 4 * kk;
            wA[kk] = *(const uint2v*)(Sb + (unsigned)sIdx[relA + j] + cbu);
            wB[kk] = *(const uint2v*)(Sb + (unsigned)sIdx[relB + j] + cbu);
          }
          unsigned pA0 = 0u, pA1 = 0u, pB0 = 0u, pB1 = 0u;
#pragma unroll
          for (int kk = 0; kk < 8; ++kk) {
            pA0 = pkadd(pA0, pkmax0(pkadd(wA[kk][0], upA[0])));
            pA1 = pkadd(pA1, pkmax0(pkadd(wA[kk][1], upA[1])));
            pB0 = pkadd(pB0, pkmax0(pkadd(wB[kk][0], upB[0])));
            pB1 = pkadd(pB1, pkmax0(pkadd(wB[kk][1], upB[1])));
          }
          f16x2 a0 = __builtin_bit_cast(f16x2, pA0), a1 = __builtin_bit_cast(f16x2, pA1);
          f16x2 b0 = __builtin_bit_cast(f16x2, pB0), b1 = __builtin_bit_cast(f16x2, pB1);
          fA0 += (float)a0[0]; fA1 += (float)a0[1]; fA2 += (float)a1[0]; fA3 += (float)a1[1];
          fB0 += (float)b0[0]; fB1 += (float)b0[1]; fB2 += (float)b1[0]; fB3 += (float)b1[1];
        }
        for (; r < rmax; ++r) {                    // masked remainder
          int base = r * 32 + q;
          uint2v wA[8], wB[8]; bool okA[8], okB[8];
#pragma unroll
          for (int kk = 0; kk < 8; ++kk) {
            int j = base + 4 * kk;
            okA[kk] = j < degA;
            wA[kk] = *(const uint2v*)(Sb + (unsigned)sIdx[relA + (okA[kk] ? j : 0)] + cbu);
            okB[kk] = j < degB;
            wB[kk] = *(const uint2v*)(Sb + (unsigned)sIdx[relB + (okB[kk] ? j : 0)] + cbu);
          }
          unsigned pA0 = 0u, pA1 = 0u, pB0 = 0u, pB1 = 0u;
#pragma unroll
          for (int kk = 0; kk < 8; ++kk) {
            unsigned zA0 = pkmax0(pkadd(wA[kk][0], upA[0]));
            unsigned zA1 = pkmax0(pkadd(wA[kk][1], upA[1]));
            pA0 = pkadd(pA0, okA[kk] ? zA0 : 0u);
            pA1 = pkadd(pA1, okA[kk] ? zA1 : 0u);
            unsigned zB0 = pkmax0(pkadd(wB[kk][0], upB[0]));
            unsigned zB1 = pkmax0(pkadd(wB[kk][1], upB[1]));
            pB0 = pkadd(pB0, okB[kk] ? zB0 : 0u);
            pB1 = pkadd(pB1, okB[kk] ? zB1 : 0u);
          }
          f16x2 a0 = __builtin_bit_cast(f16x2, pA0), a1 = __builtin_bit_cast(f16x2, pA1);
          f16x2 b0 = __builtin_bit_cast(f16x2, pB0), b1 = __builtin_bit_cast(f16x2, pB1);
          fA0 += (float)a0[0]; fA1 += (float)a0[1]; fA2 += (float)a1[0]; fA3 += (float)a1[1];
          fB0 += (float)b0[0]; fB1 += (float)b0[1]; fB2 += (float)b1[0]; fB3 += (float)b1[1];
        }
      } else {                                     // overflow fallback
        for (; r < rmax; ++r) {
          int base = r * 32 + q;
          uint2v wA[8], wB[8]; bool okA[8], okB[8];
#pragma unroll
          for (int kk = 0; kk < 8; ++kk) {
            int j = base + 4 * kk;
            okA[kk] = j < degA;
            wA[kk] = *(const uint2v*)(Sb + (unsigned)srcB[g0A + (okA[kk] ? j : 0)] + cbu);
            okB[kk] = j < degB;
            wB[kk] = *(const uint2v*)(Sb + (unsigned)srcB[g0B + (okB[kk] ? j : 0)] + cbu);
          }
          unsigned pA0 = 0u, pA1 = 0u, pB0 = 0u, pB1 = 0u;
#pragma unroll
          for (int kk = 0; kk < 8; ++kk) {
            unsigned zA0 = pkmax0(pkadd(wA[kk][0], upA[0]));
            unsigned zA1 = pkmax0(pkadd(wA[kk][1], upA[1]));
            pA0 = pkadd(pA0, okA[kk] ? zA0 : 0u);
            pA1 = pkadd(pA1, okA[kk] ? zA1 : 0u);
            unsigned zB0 = pkmax0(pkadd(wB[kk][0], upB[0]));
            unsigned zB1 = pkmax0(pkadd(wB[kk][1], upB[1]));
            pB0 = pkadd(pB0, okB[kk] ? zB0 : 0u);
            pB1 = pkadd(pB1, okB[kk] ? zB1 : 0u);
          }
          f16x2 a0 = __builtin_bit_cast(f16x2, pA0), a1 = __builtin_bit_cast(f16x2, pA1);
          f16x2 b0 = __builtin_bit_cast(f16x2, pB0), b1 = __builtin_bit_cast(f16x2, pB1);
          fA0 += (float)a0[0]; fA1 += (float)a0[1]; fA2 += (float)a1[0]; fA3 += (float)a1[1];
          fB0 += (float)b0[0]; fB1 += (float)b0[1]; fB2 += (float)b1[0]; fB3 += (float)b1[1];
        }
      }
      // reduce over edge-quarters (lanes ^16, ^32)
      fA0 += __shfl_xor(fA0, 16); fA0 += __shfl_xor(fA0, 32);
      fA1 += __shfl_xor(fA1, 16); fA1 += __shfl_xor(fA1, 32);
      fA2 += __shfl_xor(fA2, 16); fA2 += __shfl_xor(fA2, 32);
      fA3 += __shfl_xor(fA3, 16); fA3 += __shfl_xor(fA3, 32);
      fB0 += __shfl_xor(fB0, 16); fB0 += __shfl_xor(fB0, 32);
      fB1 += __shfl_xor(fB1, 16); fB1 += __shfl_xor(fB1, 32);
      fB2 += __shfl_xor(fB2, 16); fB2 += __shfl_xor(fB2, 32);
      fB3 += __shfl_xor(fB3, 16); fB3 += __shfl_xor(fB3, 32);
      if (q == 0) {
        uint2v pk;
        pk[0] = (unsigned)f2bf(fA0) | ((unsigned)f2bf(fA1) << 16);
        pk[1] = (unsigned)f2bf(fA2) | ((unsigned)f2bf(fA3) << 16);
        *(uint2v*)((char*)aggT + (size_t)lnA * 144 + cbu) = pk;
        uint2v pk2;
        pk2[0] = (unsigned)f2bf(fB0) | ((unsigned)f2bf(fB1) << 16);
        pk2[1] = (unsigned)f2bf(fB2) | ((unsigned)f2bf(fB3) << 16);
        *(uint2v*)((char*)aggT + (size_t)(lnA + 1) * 144 + cbu) = pk2;
      }
    }
  }
  __syncthreads();

  // ==== node MLP ====
  bf16x8 B1[4], B2[2];
  {
    const u16* p = NB1T + (size_t)(layer * 64 + F + n16) * 128 + quad * 8;
#pragma unroll
    for (int ks = 0; ks < 4; ++ks) B1[ks] = __builtin_bit_cast(bf16x8, *(const u16x8*)(p + ks * 32));
    const u16* q2 = M2T + (size_t)(layer * 64 + F + n16) * 64 + quad * 8;
#pragma unroll
    for (int ks = 0; ks < 2; ++ks) B2[ks] = __builtin_bit_cast(bf16x8, *(const u16x8*)(q2 + ks * 32));
  }
  float bias1 = nb1[layer * 64 + F + n16];
  float bb2f = bb2[layer * 64 + F + n16];
  float bias2 = nb2[layer * 64 + F + n16];

  // GEMM1: [h | aggT] @ NB1T (32 rows)
  f32x4 acc[2];
#pragma unroll
  for (int m = 0; m < 2; ++m) acc[m] = (f32x4){0.f, 0.f, 0.f, 0.f};
#pragma unroll
  for (int m = 0; m < 2; ++m) {
    int row = n0 + m * 16 + n16;
    if (row >= N_NODES) row = N_NODES - 1;
    const u16* hp = h + (size_t)row * 64 + quad * 8;
    const u16* ap = aggT + (m * 16 + n16) * 72 + quad * 8;
    bf16x8 a0 = __builtin_bit_cast(bf16x8, *(const u16x8*)(hp));
    bf16x8 a1 = __builtin_bit_cast(bf16x8, *(const u16x8*)(hp + 32));
    bf16x8 a2 = __builtin_bit_cast(bf16x8, *(const u16x8*)(ap));
    bf16x8 a3 = __builtin_bit_cast(bf16x8, *(const u16x8*)(ap + 32));
    acc[m] = __builtin_amdgcn_mfma_f32_16x16x32_bf16(a0, B1[0], acc[m], 0, 0, 0);
    acc[m] = __builtin_amdgcn_mfma_f32_16x16x32_bf16(a1, B1[1], acc[m], 0, 0, 0);
    acc[m] = __builtin_amdgcn_mfma_f32_16x16x32_bf16(a2, B1[2], acc[m], 0, 0, 0);
    acc[m] = __builtin_amdgcn_mfma_f32_16x16x32_bf16(a3, B1[3], acc[m], 0, 0, 0);
  }
#pragma unroll
  for (int m = 0; m < 2; ++m)
#pragma unroll
    for (int r = 0; r < 4; ++r) {
      int e = m * 16 + quad * 4 + r;
      float dg = (float)(sOff[e + 1] - sOff[e]);
      float v = acc[m][r] + bias1 + dg * bb2f;
      v = v > 0.f ? v : 0.f;
      Hs[e * 72 + F + n16] = f2bf(v);
    }
  __syncthreads();

  // GEMM2: hidden @ M2T -> h2 (registers)
  float c2[2][4];
#pragma unroll
  for (int m = 0; m < 2; ++m) {
    const u16* hp = Hs + (m * 16 + n16) * 72 + quad * 8;
    f32x4 cc = (f32x4){0.f, 0.f, 0.f, 0.f};
#pragma unroll
    for (int ks = 0; ks < 2; ++ks) {
      bf16x8 a = __builtin_bit_cast(bf16x8, *(const u16x8*)(hp + ks * 32));
      cc = __builtin_amdgcn_mfma_f32_16x16x32_bf16(a, B2[ks], cc, 0, 0, 0);
    }
#pragma unroll
    for (int r = 0; r < 4; ++r) c2[m][r] = cc[r] + bias2;
  }
  __syncthreads();   // all Hs reads done

  // h2 -> LDS (+ global if another layer follows)
#pragma unroll
  for (int m = 0; m < 2; ++m)
#pragma unroll
    for (int r = 0; r < 4; ++r) {
      int e = m * 16 + quad * 4 + r;
      u16 hv = f2bf(c2[m][r]);
      Hs[e * 72 + F + n16] = hv;
      int gn = n0 + e;
      if (layer < LAYERS - 1 && gn < N_NODES)
        hnext[(size_t)gn * 64 + F + n16] = hv;
    }
  __syncthreads();

  if (layer < LAYERS - 1) {
    int lp = layer + 1;
    bf16x8 B3[2][2];
    float w0[2], w1[2], w2[2], bb[2]; bool isU[2];
#pragma unroll
    for (int nt = 0; nt < 2; ++nt) {
      int col = wvi * 32 + nt * 16 + n16;
      const u16* p = W1abT + (size_t)(lp * 128 + col) * 64 + quad * 8;
      B3[nt][0] = __builtin_bit_cast(bf16x8, *(const u16x8*)(p));
      B3[nt][1] = __builtin_bit_cast(bf16x8, *(const u16x8*)(p + 32));
      int f = col & 63; isU[nt] = col >= 64;
      w0[nt] = Wvx[(lp * 3 + 0) * 64 + f];
      w1[nt] = Wvx[(lp * 3 + 1) * 64 + f];
      w2[nt] = Wvx[(lp * 3 + 2) * 64 + f];
      bb[nt] = b1x[lp * 64 + f];
    }
    f32x4 a3[2][2];
#pragma unroll
    for (int m = 0; m < 2; ++m)
#pragma unroll
      for (int nt = 0; nt < 2; ++nt) a3[m][nt] = (f32x4){0.f, 0.f, 0.f, 0.f};
#pragma unroll
    for (int m = 0; m < 2; ++m) {
      const u16* hp = Hs + (m * 16 + n16) * 72 + quad * 8;
      bf16x8 a0 = __builtin_bit_cast(bf16x8, *(const u16x8*)(hp));
      bf16x8 a1 = __builtin_bit_cast(bf16x8, *(const u16x8*)(hp + 32));
#pragma unroll
      for (int nt = 0; nt < 2; ++nt) {
        a3[m][nt] = __builtin_amdgcn_mfma_f32_16x16x32_bf16(a0, B3[nt][0], a3[m][nt], 0, 0, 0);
        a3[m][nt] = __builtin_amdgcn_mfma_f32_16x16x32_bf16(a1, B3[nt][1], a3[m][nt], 0, 0, 0);
      }
    }
#pragma unroll
    for (int m = 0; m < 2; ++m)
#pragma unroll
      for (int nt = 0; nt < 2; ++nt) {
        int col = wvi * 32 + nt * 16 + n16;
        int f = col & 63;
#pragma unroll
        for (int r = 0; r < 4; ++r) {
          int e = m * 16 + quad * 4 + r;
          int grow = n0 + e;
          if (grow < N_NODES) {
            float P = sPos[e * 3] * w0[nt] + sPos[e * 3 + 1] * w1[nt] + sPos[e * 3 + 2] * w2[nt];
            if (!isU[nt]) Sw[(size_t)grow * 64 + f] = f2h(a3[m][nt][r] - P);
            else          Uw[(size_t)grow * 64 + f] = f2h(a3[m][nt][r] + P + bb[nt]);
          }
        }
      }
  } else {
    // fused decoder: out = h2 @ dec_w + dec_b
    int e = t >> 3, part = t & 7;
    float s = 0.f;
#pragma unroll
    for (int j = 0; j < 8; ++j)
      s += bf2f(Hs[e * 72 + part * 8 + j]) * dec_w[part * 8 + j];
    sRed[e][part] = s;
    __syncthreads();
    if (part == 0) {
      int gn = n0 + e;
      if (gn < N_NODES) {
        float acc8 = dec_b[0];
#pragma unroll
        for (int p2 = 0; p2 < 8; ++p2) acc8 += sRed[e][p2];
        out[gn] = acc8;
      }
    }
  }
}

extern "C" void kernel_launch(void* const* d_in, const int* in_sizes, int n_in,
                              void* d_out, int out_size, void* d_ws, size_t ws_size,
                              hipStream_t stream) {
  const float* node_pos   = (const float*)d_in[0];
  const float* node_feat  = (const float*)d_in[1];
  const int*   edge_index = (const int*)d_in[2];
  const float* enc_w      = (const float*)d_in[3];
  const float* enc_b      = (const float*)d_in[4];
  const float* edge_enc_w = (const float*)d_in[5];
  const float* edge_enc_b = (const float*)d_in[6];
  const float* ew1        = (const float*)d_in[7];
  const float* eb1        = (const float*)d_in[8];
  const float* ew2        = (const float*)d_in[9];
  const float* eb2        = (const float*)d_in[10];
  const float* nw1        = (const float*)d_in[11];
  const float* nb1        = (const float*)d_in[12];
  const float* nw2        = (const float*)d_in[13];
  const float* nb2        = (const float*)d_in[14];
  const float* dec_w      = (const float*)d_in[15];
  const float* dec_b      = (const float*)d_in[16];
  float* out = (float*)d_out;

  char* ws = (char*)d_ws;
  size_t off = 0;
  u16*    hA    = (u16*)(ws + off);    off += (size_t)N_NODES * 64 * 2;
  u16*    hB    = (u16*)(ws + off);    off += (size_t)N_NODES * 64 * 2;
  u16*    S0    = (u16*)(ws + off);    off += (size_t)N_NODES * 64 * 2;
  u16*    U0    = (u16*)(ws + off);    off += (size_t)N_NODES * 64 * 2;
  u16*    S1    = (u16*)(ws + off);    off += (size_t)N_NODES * 64 * 2;
  u16*    U1    = (u16*)(ws + off);    off += (size_t)N_NODES * 64 * 2;
  u16*    W1abT = (u16*)(ws + off);    off += (size_t)LAYERS * 128 * 64 * 2;
  float*  Wvx   = (float*)(ws + off);  off += (size_t)LAYERS * 3 * 64 * 4;
  float*  b1x   = (float*)(ws + off);  off += (size_t)LAYERS * 64 * 4;
  u16*    NB1T  = (u16*)(ws + off);    off += (size_t)LAYERS * 64 * 128 * 2;
  float*  bb2   = (float*)(ws + off);  off += (size_t)LAYERS * 64 * 4;
  u16*    M2T   = (u16*)(ws + off);    off += (size_t)LAYERS * 64 * 64 * 2;
  int*    cnt      = (int*)(ws + off); off += (size_t)N_NODES * 4;
  int*    offsA    = (int*)(ws + off); off += (size_t)N_NODES * 4;  // raw scan
  int*    offsB    = (int*)(ws + off); off += (size_t)N_NODES * 4;  // finalized
  int*    partials = (int*)(ws + off); off += 32 * 4;
  int*    rank     = (int*)(ws + off); off += (size_t)N_EDGES * 4;
  int*    srcB     = (int*)(ws + off); off += (size_t)N_EDGES * 4;

  const int* dstA = edge_index + N_EDGES;

  hipMemsetAsync(cnt, 0, (size_t)N_NODES * 4, stream);

  prep_kernel<<<3125, 256, 0, stream>>>(
      node_feat, enc_w, enc_b, ew1, eb1, ew2, eb2, nw1, nw2,
      edge_enc_w, edge_enc_b, dstA,
      hA, W1abT, Wvx, b1x, NB1T, bb2, M2T, cnt, rank);

  scan1_kernel<<<SCAN_NBLK, 256, 0, stream>>>(cnt, offsA, partials);

  fss_kernel<<<NBLK32, 256, 0, stream>>>(
      hA, W1abT, Wvx, b1x, node_pos, S0, U0,
      offsA, partials, edge_index, rank, srcB, offsB);

  u16 *hc = hA, *hn = hB, *Sr = S0, *Ur = U0, *Sw = S1, *Uw = U1;
  for (int l = 0; l < LAYERS; ++l) {
    layer_kernel<<<NBLK32, 256, 0, stream>>>(hc, srcB, offsB, Sr, Ur,
                                             NB1T, nb1, bb2, M2T, nb2,
                                             hn, l, W1abT, Wvx, b1x, node_pos,
                                             Sw, Uw, dec_w, dec_b, out);
    u16* tmp;
    tmp = hc; hc = hn; hn = tmp;
    tmp = Sr; Sr = Sw; Sw = tmp;
    tmp = Ur; Ur = Uw; Uw = tmp;
  }
}